// Round 6
// baseline (319.048 us; speedup 1.0000x reference)
//
#include <hip/hip_runtime.h>
#include <hip/hip_bf16.h>

#define N_NODES 100000
#define N_EDGES 3200000
#define NFEAT 256
#define NHID 128
#define NOUT 64

#define BSHIFT 8
#define BROWS 256
#define NBUCK 391           // ceil(100000 / 256)
#define EPB 4096            // edges per block in binsort
#define NBLK1 ((N_EDGES + EPB - 1) / EPB)  // 782

typedef __attribute__((ext_vector_type(8))) short short8;
typedef __attribute__((ext_vector_type(8))) unsigned short ushort8_t;
typedef __attribute__((ext_vector_type(4))) float f32x4;

__device__ __forceinline__ unsigned short f2bf(float f) {
    union { float f; unsigned int u; } v; v.f = f;
    unsigned int r = v.u + 0x7fffu + ((v.u >> 16) & 1u);
    return (unsigned short)(r >> 16);
}
__device__ __forceinline__ float bflo(unsigned int u) { return __uint_as_float(u << 16); }
__device__ __forceinline__ float bfhi(unsigned int u) { return __uint_as_float(u & 0xffff0000u); }

// ---------------- bcount (782 blocks) + W convert (128 blocks), role by blockIdx ----

__global__ __launch_bounds__(256) void bcount_cvtw(const int* __restrict__ erow,
                                                   int* __restrict__ Mt,
                                                   const float* __restrict__ W1,
                                                   const float* __restrict__ W2,
                                                   unsigned short* __restrict__ W1b,
                                                   unsigned short* __restrict__ W2b) {
    __shared__ int h[NBUCK];
    if (blockIdx.x >= NBLK1) {
        const int i = (blockIdx.x - NBLK1) * 256 + threadIdx.x;
        if (i < NFEAT * NHID) W1b[i] = f2bf(W1[i]);
        if (i < NHID * NOUT)  W2b[i] = f2bf(W2[i]);
        return;
    }
    for (int i = threadIdx.x; i < NBUCK; i += 256) h[i] = 0;
    __syncthreads();
    const int base = blockIdx.x * EPB;
    const int n = min(EPB, N_EDGES - base);
    for (int i = threadIdx.x; i < n; i += 256)
        atomicAdd(&h[erow[base + i] >> BSHIFT], 1);
    __syncthreads();
    for (int b = threadIdx.x; b < NBUCK; b += 256)
        Mt[(size_t)b * NBLK1 + blockIdx.x] = h[b];
}

// ---------------- column scan: Mt[b][*] -> exclusive prefix (in place), btot[b] ----

__global__ __launch_bounds__(256) void colscan_kernel(int* __restrict__ Mt,
                                                      int* __restrict__ btot) {
    const int wv = threadIdx.x >> 6, lane = threadIdx.x & 63;
    const int b = blockIdx.x * 4 + wv;
    if (b >= NBUCK) return;
    int* row = Mt + (size_t)b * NBLK1;
    int carry = 0;
    for (int t = 0; t < NBLK1; t += 64) {
        int i = t + lane;
        int v = (i < NBLK1) ? row[i] : 0;
        int x = v;
        #pragma unroll
        for (int off = 1; off < 64; off <<= 1) {
            int tt = __shfl_up(x, off);
            if (lane >= off) x += tt;
        }
        if (i < NBLK1) row[i] = carry + x - v;
        carry += __shfl(x, 63);
    }
    if (lane == 0) btot[b] = carry;
}

// ---------------- bucket-total scan (one block): btot -> bbase ----------------

__global__ __launch_bounds__(1024) void bscan_kernel(const int* __restrict__ btot,
                                                     int* __restrict__ bbase) {
    __shared__ int wsum[16];
    const int tid = threadIdx.x;
    const int lane = tid & 63;
    int v = (tid < NBUCK) ? btot[tid] : 0;
    int x = v;
    #pragma unroll
    for (int off = 1; off < 64; off <<= 1) {
        int t = __shfl_up(x, off);
        if (lane >= off) x += t;
    }
    if (lane == 63) wsum[tid >> 6] = x;
    __syncthreads();
    if (tid < 16) {
        int s = wsum[tid];
        #pragma unroll
        for (int off = 1; off < 16; off <<= 1) {
            int t = __shfl_up(s, off);
            if (tid >= off) s += t;
        }
        wsum[tid] = s;
    }
    __syncthreads();
    if (tid >= 64) x += wsum[(tid >> 6) - 1];
    if (tid < NBUCK) bbase[tid] = x - v;
    if (tid == NBUCK - 1) bbase[NBUCK] = x;
}

// ---------------- binsort (standalone, 782 blocks, ~44KB LDS) ----------------------

__global__ __launch_bounds__(256) void binsort_kernel(const int* __restrict__ erow,
                                                      const int* __restrict__ ecol,
                                                      const float* __restrict__ eval,
                                                      const int* __restrict__ Mt,
                                                      const int* __restrict__ btot,
                                                      const int* __restrict__ bbase,
                                                      int2* __restrict__ tmp) {
    __shared__ int2 sc[EPB];
    __shared__ unsigned short sb[EPB];
    __shared__ int hist[NBUCK];
    __shared__ int delta[NBUCK];
    __shared__ int scan_t[4];

    const int blk = blockIdx.x;
    const int tid = threadIdx.x;
    const int base = blk * EPB;
    const int n = min(EPB, N_EDGES - base);

    int v0 = 0, v1 = 0, v2 = 0, v3 = 0;
    int m0 = 0, m1 = 0, m2 = 0, m3 = 0;
    {
        const int i0 = tid * 4;
        #define LOADCNT(k, vk, mk) { \
            int idx = i0 + k; \
            if (idx < NBUCK) { \
                mk = Mt[(size_t)idx * NBLK1 + blk]; \
                int nx = (blk + 1 < NBLK1) ? Mt[(size_t)idx * NBLK1 + blk + 1] : btot[idx]; \
                vk = nx - mk; \
            } }
        LOADCNT(0, v0, m0) LOADCNT(1, v1, m1) LOADCNT(2, v2, m2) LOADCNT(3, v3, m3)
        #undef LOADCNT
    }
    int s4 = v0 + v1 + v2 + v3;
    int xi = s4;
    const int lane = tid & 63;
    #pragma unroll
    for (int off = 1; off < 64; off <<= 1) {
        int t = __shfl_up(xi, off);
        if (lane >= off) xi += t;
    }
    if (lane == 63) scan_t[tid >> 6] = xi;
    __syncthreads();
    if (tid == 0) {
        int run = 0;
        #pragma unroll
        for (int w = 0; w < 4; ++w) { int t = scan_t[w]; scan_t[w] = run; run += t; }
    }
    __syncthreads();
    {
        int e0 = scan_t[tid >> 6] + xi - s4;
        int i0 = tid * 4;
        int ex[4] = {e0, e0 + v0, e0 + v0 + v1, e0 + v0 + v1 + v2};
        int mm[4] = {m0, m1, m2, m3};
        #pragma unroll
        for (int k = 0; k < 4; ++k) {
            int idx = i0 + k;
            if (idx < NBUCK) {
                hist[idx] = ex[k];
                delta[idx] = bbase[idx] + mm[k] - ex[k];
            }
        }
    }
    __syncthreads();

    for (int i = tid; i < n; i += 256) {
        int r = erow[base + i];
        int b = r >> BSHIFT;
        int rl = r & (BROWS - 1);
        int pos = atomicAdd(&hist[b], 1);
        sc[pos] = make_int2((rl << 17) | ecol[base + i], __float_as_int(eval[base + i]));
        sb[pos] = (unsigned short)b;
    }
    __syncthreads();

    for (int i = tid; i < n; i += 256) {
        int b = sb[i];
        tmp[delta[b] + i] = sc[i];
    }
}

// ---------------- gemm1 (standalone, 782 blocks, 32KB static LDS -> 5 blocks/CU) ----
// Y[100000,128](bf16) = X[100000,256](fp32) @ W1b[256,128](bf16)
// 2-phase K staging (bt = 128n x 128k = 32KB), XOR-swizzled; per-wave 32 rows.

__global__ __launch_bounds__(256) void gemm1_kernel(const float* __restrict__ X,
                                                    const unsigned short* __restrict__ Wb,
                                                    unsigned short* __restrict__ Y) {
    __shared__ unsigned short bt[128 * 128];   // [n][kk] kk in [0,128)
    const int bid = blockIdx.x;
    const int tid = threadIdx.x;
    const int lane = tid & 63;
    const int w = tid >> 6;
    const int rb = bid * 128 + w * 32;
    const int lr = lane & 15;
    const int kg = lane >> 4;
    const int M = N_NODES;

    f32x4 acc[2][8];
    #pragma unroll
    for (int a = 0; a < 2; ++a)
        #pragma unroll
        for (int nf = 0; nf < 8; ++nf)
            #pragma unroll
            for (int i = 0; i < 4; ++i) acc[a][nf][i] = 0.f;

    for (int ph = 0; ph < 2; ++ph) {
        if (ph) __syncthreads();   // all waves done reading bt before restage
        {
            const int nn = tid & 127;
            const int kb = tid >> 7;         // 0..1
            #pragma unroll
            for (int kk0 = 0; kk0 < 64; kk0 += 8) {
                const int kk = kb * 64 + kk0;
                unsigned short p[8];
                #pragma unroll
                for (int i = 0; i < 8; ++i)
                    p[i] = Wb[(size_t)(ph * 128 + kk + i) * NHID + nn];
                unsigned int byte = (unsigned int)nn * 256 + (unsigned int)kk * 2;
                byte ^= (unsigned int)(nn & 7) << 4;
                *(ushort8_t*)((char*)bt + byte) = *(const ushort8_t*)p;
            }
        }
        __syncthreads();

        #pragma unroll
        for (int ks = 0; ks < 4; ++ks) {
            const int k0 = ph * 128 + ks * 32 + kg * 8;
            short8 a0, a1;
            #pragma unroll
            for (int af = 0; af < 2; ++af) {
                const int row = rb + af * 16 + lr;
                short8 r;
                if (row < M) {
                    const float* p = X + (size_t)row * NFEAT + k0;
                    float4 u0 = *(const float4*)p;
                    float4 u1 = *(const float4*)(p + 4);
                    unsigned short q[8] = {f2bf(u0.x), f2bf(u0.y), f2bf(u0.z), f2bf(u0.w),
                                           f2bf(u1.x), f2bf(u1.y), f2bf(u1.z), f2bf(u1.w)};
                    r = *(const short8*)q;
                } else {
                    #pragma unroll
                    for (int i = 0; i < 8; ++i) r[i] = 0;
                }
                if (af == 0) a0 = r; else a1 = r;
            }
            #pragma unroll
            for (int nf = 0; nf < 8; ++nf) {
                const int nn = nf * 16 + lr;
                unsigned int byte = (unsigned int)nn * 256 + (unsigned int)(ks * 32 + kg * 8) * 2;
                byte ^= (unsigned int)(nn & 7) << 4;
                short8 bfr = *(const short8*)((const char*)bt + byte);
                acc[0][nf] = __builtin_amdgcn_mfma_f32_16x16x32_bf16(a0, bfr, acc[0][nf], 0, 0, 0);
                acc[1][nf] = __builtin_amdgcn_mfma_f32_16x16x32_bf16(a1, bfr, acc[1][nf], 0, 0, 0);
            }
        }
    }

    #pragma unroll
    for (int af = 0; af < 2; ++af)
        #pragma unroll
        for (int nf = 0; nf < 8; ++nf)
            #pragma unroll
            for (int i = 0; i < 4; ++i) {
                const int r = rb + af * 16 + kg * 4 + i;
                if (r < M) Y[(size_t)r * NHID + nf * 16 + lr] = f2bf(acc[af][nf][i]);
            }
}

// ---------------- rowsort: per-256-row-bucket sort + rowptr (tmp -> ec2) -----------

__global__ __launch_bounds__(256) void rowsort_kernel(const int* __restrict__ bbase,
                                                      const int2* __restrict__ tmp,
                                                      int2* __restrict__ ec2,
                                                      int* __restrict__ rowptr) {
    __shared__ int h[BROWS];
    __shared__ int hx[BROWS];
    __shared__ int wq[4];

    const int b = blockIdx.x;
    const int s = bbase[b], e = bbase[b + 1];
    const int n = e - s;
    const int tid = threadIdx.x;
    const int lane = tid & 63;

    h[tid] = 0;
    __syncthreads();
    for (int i = tid; i < n; i += 256)
        atomicAdd(&h[((unsigned)tmp[s + i].x) >> 17], 1);
    __syncthreads();

    int v = h[tid];
    int x = v;
    #pragma unroll
    for (int off = 1; off < 64; off <<= 1) {
        int t = __shfl_up(x, off);
        if (lane >= off) x += t;
    }
    if (lane == 63) wq[tid >> 6] = x;
    __syncthreads();
    if (tid == 0) {
        int run = 0;
        #pragma unroll
        for (int w = 0; w < 4; ++w) { int t = wq[w]; wq[w] = run; run += t; }
    }
    __syncthreads();
    x += wq[tid >> 6];
    {
        const int grow = b * BROWS + tid;
        if (grow < N_NODES) rowptr[grow + 1] = s + x;
        if (b == 0 && tid == 0) rowptr[0] = 0;
        hx[tid] = s + (x - v);
    }
    __syncthreads();

    for (int i = tid; i < n; i += 256) {
        int2 d = tmp[s + i];
        unsigned int rl = ((unsigned)d.x) >> 17;
        int pos = atomicAdd(&hx[rl], 1);
        ec2[pos] = make_int2(d.x & 0x1FFFF, d.y);
    }
}

// ---------------- gemm2 (template, bf16 A, pre-converted W): Y = X @ Wb -------------

template<int N, int K>
__global__ __launch_bounds__(256) void gemm_mfma(const unsigned short* __restrict__ X,
                                                 const unsigned short* __restrict__ Wb,
                                                 unsigned short* __restrict__ Y, int M) {
    __shared__ unsigned short bt[N * K];
    const int tid = threadIdx.x;

    {
        const int n = tid & (N - 1);
        const int kb = tid / N;
        const int kspan = K / (256 / N);
        for (int k0 = kb * kspan; k0 < (kb + 1) * kspan; k0 += 8) {
            unsigned short p[8];
            #pragma unroll
            for (int i = 0; i < 8; ++i) p[i] = Wb[(size_t)(k0 + i) * N + n];
            unsigned int byte = (unsigned int)n * (K * 2) + (unsigned int)k0 * 2;
            byte ^= (unsigned int)(n & 7) << 4;
            *(ushort8_t*)((char*)bt + byte) = *(const ushort8_t*)p;
        }
    }
    __syncthreads();

    const int lane = tid & 63;
    const int w = tid >> 6;
    const int rb = blockIdx.x * 128 + w * 32;
    const int lr = lane & 15;
    const int kg = lane >> 4;
    constexpr int NF = N / 16;
    constexpr int KS = K / 32;

    f32x4 acc[2][NF];
    #pragma unroll
    for (int a = 0; a < 2; ++a)
        #pragma unroll
        for (int nf = 0; nf < NF; ++nf)
            #pragma unroll
            for (int i = 0; i < 4; ++i) acc[a][nf][i] = 0.f;

    auto loadA = [&](int af, int ks) -> short8 {
        const int row = rb + af * 16 + lr;
        const int k0 = ks * 32 + kg * 8;
        short8 r;
        if (row < M) {
            r = *(const short8*)(X + (size_t)row * K + k0);
        } else {
            #pragma unroll
            for (int i = 0; i < 8; ++i) r[i] = 0;
        }
        return r;
    };
    auto loadB = [&](int nf, int ks) -> short8 {
        const int n = nf * 16 + lr;
        unsigned int byte = (unsigned int)n * (K * 2) + (unsigned int)(ks * 32 + kg * 8) * 2;
        byte ^= (unsigned int)(n & 7) << 4;
        return *(const short8*)((const char*)bt + byte);
    };

    #pragma unroll
    for (int ks = 0; ks < KS; ++ks) {
        short8 a0 = loadA(0, ks), a1 = loadA(1, ks);
        #pragma unroll
        for (int nf = 0; nf < NF; ++nf) {
            short8 bfr = loadB(nf, ks);
            acc[0][nf] = __builtin_amdgcn_mfma_f32_16x16x32_bf16(a0, bfr, acc[0][nf], 0, 0, 0);
            acc[1][nf] = __builtin_amdgcn_mfma_f32_16x16x32_bf16(a1, bfr, acc[1][nf], 0, 0, 0);
        }
    }

    #pragma unroll
    for (int af = 0; af < 2; ++af)
        #pragma unroll
        for (int nf = 0; nf < NF; ++nf)
            #pragma unroll
            for (int i = 0; i < 4; ++i) {
                const int r = rb + af * 16 + kg * 4 + i;
                if (r < M) Y[(size_t)r * N + nf * 16 + lr] = f2bf(acc[af][nf][i]);
            }
}

// ---------------- SpMM layer 1: F=128, full-wave 4B/lane, 16 gathers in flight ------

__global__ __launch_bounds__(256) void spmm1_kernel(const int* __restrict__ rp,
                                                    const int2* __restrict__ ec,
                                                    const unsigned int* __restrict__ d32,
                                                    const float* __restrict__ bias,
                                                    unsigned short* __restrict__ out) {
    const int lane = threadIdx.x & 63;
    const int row = blockIdx.x * 4 + (threadIdx.x >> 6);
    if (row >= N_NODES) return;
    const int s = __builtin_amdgcn_readfirstlane(rp[row]);
    const int e = __builtin_amdgcn_readfirstlane(rp[row + 1]);
    float a0 = 0.f, a1 = 0.f, b0 = 0.f, b1 = 0.f;
    float c0a = 0.f, c1a = 0.f, d0a = 0.f, d1a = 0.f;
    int j = s;
    for (; j + 16 <= e; j += 16) {
        int2 q0 = ec[j],      q1 = ec[j + 1],  q2 = ec[j + 2],  q3 = ec[j + 3];
        int2 q4 = ec[j + 4],  q5 = ec[j + 5],  q6 = ec[j + 6],  q7 = ec[j + 7];
        int2 q8 = ec[j + 8],  q9 = ec[j + 9],  qa = ec[j + 10], qb = ec[j + 11];
        int2 qc = ec[j + 12], qd = ec[j + 13], qe = ec[j + 14], qf = ec[j + 15];
        unsigned int u0 = d32[(size_t)q0.x * 64 + lane];
        unsigned int u1 = d32[(size_t)q1.x * 64 + lane];
        unsigned int u2 = d32[(size_t)q2.x * 64 + lane];
        unsigned int u3 = d32[(size_t)q3.x * 64 + lane];
        unsigned int u4 = d32[(size_t)q4.x * 64 + lane];
        unsigned int u5 = d32[(size_t)q5.x * 64 + lane];
        unsigned int u6 = d32[(size_t)q6.x * 64 + lane];
        unsigned int u7 = d32[(size_t)q7.x * 64 + lane];
        unsigned int u8 = d32[(size_t)q8.x * 64 + lane];
        unsigned int u9 = d32[(size_t)q9.x * 64 + lane];
        unsigned int ua = d32[(size_t)qa.x * 64 + lane];
        unsigned int ub = d32[(size_t)qb.x * 64 + lane];
        unsigned int uc = d32[(size_t)qc.x * 64 + lane];
        unsigned int ud = d32[(size_t)qd.x * 64 + lane];
        unsigned int ue = d32[(size_t)qe.x * 64 + lane];
        unsigned int uf = d32[(size_t)qf.x * 64 + lane];
        float v0 = __int_as_float(q0.y), v1 = __int_as_float(q1.y);
        float v2 = __int_as_float(q2.y), v3 = __int_as_float(q3.y);
        float v4 = __int_as_float(q4.y), v5 = __int_as_float(q5.y);
        float v6 = __int_as_float(q6.y), v7 = __int_as_float(q7.y);
        float v8 = __int_as_float(q8.y), v9 = __int_as_float(q9.y);
        float va = __int_as_float(qa.y), vb = __int_as_float(qb.y);
        float vc = __int_as_float(qc.y), vd = __int_as_float(qd.y);
        float ve = __int_as_float(qe.y), vf = __int_as_float(qf.y);
        a0 += v0 * bflo(u0); a1 += v0 * bfhi(u0);
        b0 += v1 * bflo(u1); b1 += v1 * bfhi(u1);
        c0a += v2 * bflo(u2); c1a += v2 * bfhi(u2);
        d0a += v3 * bflo(u3); d1a += v3 * bfhi(u3);
        a0 += v4 * bflo(u4); a1 += v4 * bfhi(u4);
        b0 += v5 * bflo(u5); b1 += v5 * bfhi(u5);
        c0a += v6 * bflo(u6); c1a += v6 * bfhi(u6);
        d0a += v7 * bflo(u7); d1a += v7 * bfhi(u7);
        a0 += v8 * bflo(u8); a1 += v8 * bfhi(u8);
        b0 += v9 * bflo(u9); b1 += v9 * bfhi(u9);
        c0a += va * bflo(ua); c1a += va * bfhi(ua);
        d0a += vb * bflo(ub); d1a += vb * bfhi(ub);
        a0 += vc * bflo(uc); a1 += vc * bfhi(uc);
        b0 += vd * bflo(ud); b1 += vd * bfhi(ud);
        c0a += ve * bflo(ue); c1a += ve * bfhi(ue);
        d0a += vf * bflo(uf); d1a += vf * bfhi(uf);
    }
    for (; j + 8 <= e; j += 8) {
        int2 q0 = ec[j],     q1 = ec[j + 1], q2 = ec[j + 2], q3 = ec[j + 3];
        int2 q4 = ec[j + 4], q5 = ec[j + 5], q6 = ec[j + 6], q7 = ec[j + 7];
        unsigned int u0 = d32[(size_t)q0.x * 64 + lane];
        unsigned int u1 = d32[(size_t)q1.x * 64 + lane];
        unsigned int u2 = d32[(size_t)q2.x * 64 + lane];
        unsigned int u3 = d32[(size_t)q3.x * 64 + lane];
        unsigned int u4 = d32[(size_t)q4.x * 64 + lane];
        unsigned int u5 = d32[(size_t)q5.x * 64 + lane];
        unsigned int u6 = d32[(size_t)q6.x * 64 + lane];
        unsigned int u7 = d32[(size_t)q7.x * 64 + lane];
        float v0 = __int_as_float(q0.y), v1 = __int_as_float(q1.y);
        float v2 = __int_as_float(q2.y), v3 = __int_as_float(q3.y);
        float v4 = __int_as_float(q4.y), v5 = __int_as_float(q5.y);
        float v6 = __int_as_float(q6.y), v7 = __int_as_float(q7.y);
        a0 += v0 * bflo(u0); a1 += v0 * bfhi(u0);
        b0 += v1 * bflo(u1); b1 += v1 * bfhi(u1);
        c0a += v2 * bflo(u2); c1a += v2 * bfhi(u2);
        d0a += v3 * bflo(u3); d1a += v3 * bfhi(u3);
        a0 += v4 * bflo(u4); a1 += v4 * bfhi(u4);
        b0 += v5 * bflo(u5); b1 += v5 * bfhi(u5);
        c0a += v6 * bflo(u6); c1a += v6 * bfhi(u6);
        d0a += v7 * bflo(u7); d1a += v7 * bfhi(u7);
    }
    for (; j < e; ++j) {
        int2 c = ec[j];
        float v = __int_as_float(c.y);
        unsigned int u = d32[(size_t)c.x * 64 + lane];
        a0 += v * bflo(u);
        a1 += v * bfhi(u);
    }
    a0 += b0 + c0a + d0a; a1 += b1 + c1a + d1a;
    float2 bp = *(const float2*)(bias + 2 * lane);
    float r0 = fmaxf(a0 + bp.x, 0.f);
    float r1 = fmaxf(a1 + bp.y, 0.f);
    unsigned int pack = (unsigned int)f2bf(r0) | ((unsigned int)f2bf(r1) << 16);
    *(unsigned int*)(out + (size_t)row * 128 + 2 * lane) = pack;
}

// ---------------- SpMM layer 2: F=64, half-wave 4B/lane, 16 edges (8/half) ----------

__global__ __launch_bounds__(256) void spmm2_kernel(const int* __restrict__ rp,
                                                    const int2* __restrict__ ec,
                                                    const unsigned int* __restrict__ d32,
                                                    const float* __restrict__ bias,
                                                    float* __restrict__ out) {
    const int lane = threadIdx.x & 63;
    const int row = blockIdx.x * 4 + (threadIdx.x >> 6);
    if (row >= N_NODES) return;
    const int s = __builtin_amdgcn_readfirstlane(rp[row]);
    const int e = __builtin_amdgcn_readfirstlane(rp[row + 1]);
    const int eh = lane >> 5, cl = lane & 31;
    float a0 = 0.f, a1 = 0.f, b0 = 0.f, b1 = 0.f;
    float c0a = 0.f, c1a = 0.f, d0a = 0.f, d1a = 0.f;
    int j = s;
    for (; j + 16 <= e; j += 16) {
        int2 q0 = ec[j + eh],      q1 = ec[j + 2 + eh];
        int2 q2 = ec[j + 4 + eh],  q3 = ec[j + 6 + eh];
        int2 q4 = ec[j + 8 + eh],  q5 = ec[j + 10 + eh];
        int2 q6 = ec[j + 12 + eh], q7 = ec[j + 14 + eh];
        unsigned int u0 = d32[(size_t)q0.x * 32 + cl];
        unsigned int u1 = d32[(size_t)q1.x * 32 + cl];
        unsigned int u2 = d32[(size_t)q2.x * 32 + cl];
        unsigned int u3 = d32[(size_t)q3.x * 32 + cl];
        unsigned int u4 = d32[(size_t)q4.x * 32 + cl];
        unsigned int u5 = d32[(size_t)q5.x * 32 + cl];
        unsigned int u6 = d32[(size_t)q6.x * 32 + cl];
        unsigned int u7 = d32[(size_t)q7.x * 32 + cl];
        float v0 = __int_as_float(q0.y), v1 = __int_as_float(q1.y);
        float v2 = __int_as_float(q2.y), v3 = __int_as_float(q3.y);
        float v4 = __int_as_float(q4.y), v5 = __int_as_float(q5.y);
        float v6 = __int_as_float(q6.y), v7 = __int_as_float(q7.y);
        a0 += v0 * bflo(u0); a1 += v0 * bfhi(u0);
        b0 += v1 * bflo(u1); b1 += v1 * bfhi(u1);
        c0a += v2 * bflo(u2); c1a += v2 * bfhi(u2);
        d0a += v3 * bflo(u3); d1a += v3 * bfhi(u3);
        a0 += v4 * bflo(u4); a1 += v4 * bfhi(u4);
        b0 += v5 * bflo(u5); b1 += v5 * bfhi(u5);
        c0a += v6 * bflo(u6); c1a += v6 * bfhi(u6);
        d0a += v7 * bflo(u7); d1a += v7 * bfhi(u7);
    }
    for (; j + 8 <= e; j += 8) {
        int2 q0 = ec[j + eh],     q1 = ec[j + 2 + eh];
        int2 q2 = ec[j + 4 + eh], q3 = ec[j + 6 + eh];
        unsigned int u0 = d32[(size_t)q0.x * 32 + cl];
        unsigned int u1 = d32[(size_t)q1.x * 32 + cl];
        unsigned int u2 = d32[(size_t)q2.x * 32 + cl];
        unsigned int u3 = d32[(size_t)q3.x * 32 + cl];
        float v0 = __int_as_float(q0.y), v1 = __int_as_float(q1.y);
        float v2 = __int_as_float(q2.y), v3 = __int_as_float(q3.y);
        a0 += v0 * bflo(u0); a1 += v0 * bfhi(u0);
        b0 += v1 * bflo(u1); b1 += v1 * bfhi(u1);
        c0a += v2 * bflo(u2); c1a += v2 * bfhi(u2);
        d0a += v3 * bflo(u3); d1a += v3 * bfhi(u3);
    }
    for (; j < e; j += 2) {
        const int j2 = j + eh;
        if (j2 < e) {
            int2 cv = ec[j2];
            float v = __int_as_float(cv.y);
            unsigned int u = d32[(size_t)cv.x * 32 + cl];
            a0 += v * bflo(u);
            a1 += v * bfhi(u);
        }
    }
    a0 += b0 + c0a + d0a; a1 += b1 + c1a + d1a;
    a0 += __shfl_xor(a0, 32);
    a1 += __shfl_xor(a1, 32);
    if (eh == 0) {
        float2 bp = *(const float2*)(bias + 2 * cl);
        *(float2*)(out + (size_t)row * 64 + 2 * cl) = make_float2(a0 + bp.x, a1 + bp.y);
    }
}

// ---------------- launch ----------------

extern "C" void kernel_launch(void* const* d_in, const int* in_sizes, int n_in,
                              void* d_out, int out_size, void* d_ws, size_t ws_size,
                              hipStream_t stream) {
    const float* x    = (const float*)d_in[0];
    const int*   erow = (const int*)d_in[1];
    const int*   ecol = (const int*)d_in[2];
    const float* evalv = (const float*)d_in[3];
    const float* W1   = (const float*)d_in[4];
    const float* b1   = (const float*)d_in[5];
    const float* W2   = (const float*)d_in[6];
    const float* b2   = (const float*)d_in[7];
    float* out = (float*)d_out;

    char* wsp = (char*)d_ws;
    size_t off = 0;
    auto alloc = [&](size_t bytes) -> void* {
        void* p = wsp + off;
        off = (off + bytes + 255) & ~(size_t)255;
        return p;
    };
    unsigned short* support = (unsigned short*)alloc((size_t)N_NODES * NHID * 2);
    unsigned short* hbuf    = (unsigned short*)alloc((size_t)N_NODES * NHID * 2);
    int2*  tmp     = (int2*)alloc((size_t)N_EDGES * 8);   // bucket-sorted (pass 1)
    int2*  ec2     = (int2*)alloc((size_t)N_EDGES * 8);   // row-sorted (pass 2)
    int*   Mt      = (int*)alloc((size_t)NBUCK * NBLK1 * 4);
    int*   btot    = (int*)alloc((size_t)NBUCK * 4);
    int*   bbase   = (int*)alloc((size_t)(NBUCK + 1) * 4);
    int*   rowptr  = (int*)alloc((size_t)(N_NODES + 1) * 4);
    unsigned short* W1b = (unsigned short*)alloc((size_t)NFEAT * NHID * 2);
    unsigned short* W2b = (unsigned short*)alloc((size_t)NHID * NOUT * 2);

    bcount_cvtw<<<NBLK1 + 128, 256, 0, stream>>>(erow, Mt, W1, W2, W1b, W2b);
    colscan_kernel<<<(NBUCK + 3) / 4, 256, 0, stream>>>(Mt, btot);
    bscan_kernel<<<1, 1024, 0, stream>>>(btot, bbase);
    binsort_kernel<<<NBLK1, 256, 0, stream>>>(erow, ecol, evalv, Mt, btot, bbase, tmp);
    gemm1_kernel<<<(N_NODES + 127) / 128, 256, 0, stream>>>(x, W1b, support);
    rowsort_kernel<<<NBUCK, 256, 0, stream>>>(bbase, tmp, ec2, rowptr);

    spmm1_kernel<<<(N_NODES + 3) / 4, 256, 0, stream>>>(rowptr, ec2, (const unsigned int*)support, b1, hbuf);
    gemm_mfma<NOUT, NHID><<<(N_NODES + 127) / 128, 256, 0, stream>>>(hbuf, W2b, support, N_NODES);
    spmm2_kernel<<<(N_NODES + 3) / 4, 256, 0, stream>>>(rowptr, ec2, (const unsigned int*)support, b2, out);
}

// Round 7
// 308.404 us; speedup vs baseline: 1.0345x; 1.0345x over previous
//
#include <hip/hip_runtime.h>
#include <hip/hip_bf16.h>

#define N_NODES 100000
#define N_EDGES 3200000
#define NFEAT 256
#define NHID 128
#define NOUT 64

#define BSHIFT 8
#define BROWS 256
#define NBUCK 391           // ceil(100000 / 256)
#define EPB 4096            // edges per block in binsort
#define NBLK1 ((N_EDGES + EPB - 1) / EPB)  // 782
#define GB1 782             // gemm1 row-blocks: ceil(100000/128)

typedef __attribute__((ext_vector_type(8))) short short8;
typedef __attribute__((ext_vector_type(8))) unsigned short ushort8_t;
typedef __attribute__((ext_vector_type(4))) float f32x4;

__device__ __forceinline__ unsigned short f2bf(float f) {
    union { float f; unsigned int u; } v; v.f = f;
    unsigned int r = v.u + 0x7fffu + ((v.u >> 16) & 1u);
    return (unsigned short)(r >> 16);
}
__device__ __forceinline__ float bflo(unsigned int u) { return __uint_as_float(u << 16); }
__device__ __forceinline__ float bfhi(unsigned int u) { return __uint_as_float(u & 0xffff0000u); }

// ---------------- bcount (782 blocks) + W convert (128 blocks), role by blockIdx ----

__global__ __launch_bounds__(256) void bcount_cvtw(const int* __restrict__ erow,
                                                   int* __restrict__ Mt,
                                                   const float* __restrict__ W1,
                                                   const float* __restrict__ W2,
                                                   unsigned short* __restrict__ W1b,
                                                   unsigned short* __restrict__ W2b) {
    __shared__ int h[NBUCK];
    if (blockIdx.x >= NBLK1) {
        const int i = (blockIdx.x - NBLK1) * 256 + threadIdx.x;
        if (i < NFEAT * NHID) W1b[i] = f2bf(W1[i]);
        if (i < NHID * NOUT)  W2b[i] = f2bf(W2[i]);
        return;
    }
    for (int i = threadIdx.x; i < NBUCK; i += 256) h[i] = 0;
    __syncthreads();
    const int base = blockIdx.x * EPB;
    const int n = min(EPB, N_EDGES - base);
    for (int i = threadIdx.x; i < n; i += 256)
        atomicAdd(&h[erow[base + i] >> BSHIFT], 1);
    __syncthreads();
    for (int b = threadIdx.x; b < NBUCK; b += 256)
        Mt[(size_t)b * NBLK1 + blockIdx.x] = h[b];
}

// ---------------- column scan: Mt[b][*] -> exclusive prefix (in place), btot[b] ----

__global__ __launch_bounds__(256) void colscan_kernel(int* __restrict__ Mt,
                                                      int* __restrict__ btot) {
    const int wv = threadIdx.x >> 6, lane = threadIdx.x & 63;
    const int b = blockIdx.x * 4 + wv;
    if (b >= NBUCK) return;
    int* row = Mt + (size_t)b * NBLK1;
    int carry = 0;
    for (int t = 0; t < NBLK1; t += 64) {
        int i = t + lane;
        int v = (i < NBLK1) ? row[i] : 0;
        int x = v;
        #pragma unroll
        for (int off = 1; off < 64; off <<= 1) {
            int tt = __shfl_up(x, off);
            if (lane >= off) x += tt;
        }
        if (i < NBLK1) row[i] = carry + x - v;
        carry += __shfl(x, 63);
    }
    if (lane == 0) btot[b] = carry;
}

// ---------------- bucket-total scan (one block): btot -> bbase ----------------

__global__ __launch_bounds__(1024) void bscan_kernel(const int* __restrict__ btot,
                                                     int* __restrict__ bbase) {
    __shared__ int wsum[16];
    const int tid = threadIdx.x;
    const int lane = tid & 63;
    int v = (tid < NBUCK) ? btot[tid] : 0;
    int x = v;
    #pragma unroll
    for (int off = 1; off < 64; off <<= 1) {
        int t = __shfl_up(x, off);
        if (lane >= off) x += t;
    }
    if (lane == 63) wsum[tid >> 6] = x;
    __syncthreads();
    if (tid < 16) {
        int s = wsum[tid];
        #pragma unroll
        for (int off = 1; off < 16; off <<= 1) {
            int t = __shfl_up(s, off);
            if (tid >= off) s += t;
        }
        wsum[tid] = s;
    }
    __syncthreads();
    if (tid >= 64) x += wsum[(tid >> 6) - 1];
    if (tid < NBUCK) bbase[tid] = x - v;
    if (tid == NBUCK - 1) bbase[NBUCK] = x;
}

// ---------------- binsort (standalone, 782 blocks, ~44KB LDS) ----------------------

__global__ __launch_bounds__(256) void binsort_kernel(const int* __restrict__ erow,
                                                      const int* __restrict__ ecol,
                                                      const float* __restrict__ eval,
                                                      const int* __restrict__ Mt,
                                                      const int* __restrict__ btot,
                                                      const int* __restrict__ bbase,
                                                      int2* __restrict__ tmp) {
    __shared__ int2 sc[EPB];
    __shared__ unsigned short sb[EPB];
    __shared__ int hist[NBUCK];
    __shared__ int delta[NBUCK];
    __shared__ int scan_t[4];

    const int blk = blockIdx.x;
    const int tid = threadIdx.x;
    const int base = blk * EPB;
    const int n = min(EPB, N_EDGES - base);

    int v0 = 0, v1 = 0, v2 = 0, v3 = 0;
    int m0 = 0, m1 = 0, m2 = 0, m3 = 0;
    {
        const int i0 = tid * 4;
        #define LOADCNT(k, vk, mk) { \
            int idx = i0 + k; \
            if (idx < NBUCK) { \
                mk = Mt[(size_t)idx * NBLK1 + blk]; \
                int nx = (blk + 1 < NBLK1) ? Mt[(size_t)idx * NBLK1 + blk + 1] : btot[idx]; \
                vk = nx - mk; \
            } }
        LOADCNT(0, v0, m0) LOADCNT(1, v1, m1) LOADCNT(2, v2, m2) LOADCNT(3, v3, m3)
        #undef LOADCNT
    }
    int s4 = v0 + v1 + v2 + v3;
    int xi = s4;
    const int lane = tid & 63;
    #pragma unroll
    for (int off = 1; off < 64; off <<= 1) {
        int t = __shfl_up(xi, off);
        if (lane >= off) xi += t;
    }
    if (lane == 63) scan_t[tid >> 6] = xi;
    __syncthreads();
    if (tid == 0) {
        int run = 0;
        #pragma unroll
        for (int w = 0; w < 4; ++w) { int t = scan_t[w]; scan_t[w] = run; run += t; }
    }
    __syncthreads();
    {
        int e0 = scan_t[tid >> 6] + xi - s4;
        int i0 = tid * 4;
        int ex[4] = {e0, e0 + v0, e0 + v0 + v1, e0 + v0 + v1 + v2};
        int mm[4] = {m0, m1, m2, m3};
        #pragma unroll
        for (int k = 0; k < 4; ++k) {
            int idx = i0 + k;
            if (idx < NBUCK) {
                hist[idx] = ex[k];
                delta[idx] = bbase[idx] + mm[k] - ex[k];
            }
        }
    }
    __syncthreads();

    for (int i = tid; i < n; i += 256) {
        int r = erow[base + i];
        int b = r >> BSHIFT;
        int rl = r & (BROWS - 1);
        int pos = atomicAdd(&hist[b], 1);
        sc[pos] = make_int2((rl << 17) | ecol[base + i], __float_as_int(eval[base + i]));
        sb[pos] = (unsigned short)b;
    }
    __syncthreads();

    for (int i = tid; i < n; i += 256) {
        int b = sb[i];
        tmp[delta[b] + i] = sc[i];
    }
}

// ---------------- fused rowsort (391 blocks) + gemm1 (782 blocks) -------------------
// gemm1 is independent of the sort chain; rowsort leaves the GPU ~85% idle (391
// blocks, LDS-atomic-bound). Fusing overlaps gemm1's X-stream+MFMA under rowsort.
// 32KB dynamic LDS -> 5 blocks/CU -> all 1173 blocks co-resident.

__device__ __forceinline__ void gemm1_role(int bid, char* sm,
                                           const float* __restrict__ X,
                                           const unsigned short* __restrict__ Wb,
                                           unsigned short* __restrict__ Y) {
    unsigned short* bt = (unsigned short*)sm;   // [n][kk] kk in [0,128), 32KB
    const int tid = threadIdx.x;
    const int lane = tid & 63;
    const int w = tid >> 6;
    const int rb = bid * 128 + w * 32;
    const int lr = lane & 15;
    const int kg = lane >> 4;
    const int M = N_NODES;

    f32x4 acc[2][8];
    #pragma unroll
    for (int a = 0; a < 2; ++a)
        #pragma unroll
        for (int nf = 0; nf < 8; ++nf)
            #pragma unroll
            for (int i = 0; i < 4; ++i) acc[a][nf][i] = 0.f;

    for (int ph = 0; ph < 2; ++ph) {
        if (ph) __syncthreads();   // all waves done reading bt before restage
        {
            const int nn = tid & 127;
            const int kb = tid >> 7;         // 0..1
            #pragma unroll
            for (int kk0 = 0; kk0 < 64; kk0 += 8) {
                const int kk = kb * 64 + kk0;
                unsigned short p[8];
                #pragma unroll
                for (int i = 0; i < 8; ++i)
                    p[i] = Wb[(size_t)(ph * 128 + kk + i) * NHID + nn];
                unsigned int byte = (unsigned int)nn * 256 + (unsigned int)kk * 2;
                byte ^= (unsigned int)(nn & 7) << 4;
                *(ushort8_t*)((char*)bt + byte) = *(const ushort8_t*)p;
            }
        }
        __syncthreads();

        #pragma unroll
        for (int ks = 0; ks < 4; ++ks) {
            const int k0 = ph * 128 + ks * 32 + kg * 8;
            short8 a0, a1;
            #pragma unroll
            for (int af = 0; af < 2; ++af) {
                const int row = rb + af * 16 + lr;
                short8 r;
                if (row < M) {
                    const float* p = X + (size_t)row * NFEAT + k0;
                    float4 u0 = *(const float4*)p;
                    float4 u1 = *(const float4*)(p + 4);
                    unsigned short q[8] = {f2bf(u0.x), f2bf(u0.y), f2bf(u0.z), f2bf(u0.w),
                                           f2bf(u1.x), f2bf(u1.y), f2bf(u1.z), f2bf(u1.w)};
                    r = *(const short8*)q;
                } else {
                    #pragma unroll
                    for (int i = 0; i < 8; ++i) r[i] = 0;
                }
                if (af == 0) a0 = r; else a1 = r;
            }
            #pragma unroll
            for (int nf = 0; nf < 8; ++nf) {
                const int nn = nf * 16 + lr;
                unsigned int byte = (unsigned int)nn * 256 + (unsigned int)(ks * 32 + kg * 8) * 2;
                byte ^= (unsigned int)(nn & 7) << 4;
                short8 bfr = *(const short8*)((const char*)bt + byte);
                acc[0][nf] = __builtin_amdgcn_mfma_f32_16x16x32_bf16(a0, bfr, acc[0][nf], 0, 0, 0);
                acc[1][nf] = __builtin_amdgcn_mfma_f32_16x16x32_bf16(a1, bfr, acc[1][nf], 0, 0, 0);
            }
        }
    }

    #pragma unroll
    for (int af = 0; af < 2; ++af)
        #pragma unroll
        for (int nf = 0; nf < 8; ++nf)
            #pragma unroll
            for (int i = 0; i < 4; ++i) {
                const int r = rb + af * 16 + kg * 4 + i;
                if (r < M) Y[(size_t)r * NHID + nf * 16 + lr] = f2bf(acc[af][nf][i]);
            }
}

__device__ __forceinline__ void rowsort_role(int b, char* sm,
                                             const int* __restrict__ bbase,
                                             const int2* __restrict__ tmp,
                                             int2* __restrict__ ec2,
                                             int* __restrict__ rowptr) {
    int* h  = (int*)sm;            // [256]
    int* hx = (int*)(sm + 1024);   // [256]
    int* wq = (int*)(sm + 2048);   // [4]

    const int s = bbase[b], e = bbase[b + 1];
    const int n = e - s;
    const int tid = threadIdx.x;
    const int lane = tid & 63;

    h[tid] = 0;
    __syncthreads();
    for (int i = tid; i < n; i += 256)
        atomicAdd(&h[((unsigned)tmp[s + i].x) >> 17], 1);
    __syncthreads();

    int v = h[tid];
    int x = v;
    #pragma unroll
    for (int off = 1; off < 64; off <<= 1) {
        int t = __shfl_up(x, off);
        if (lane >= off) x += t;
    }
    if (lane == 63) wq[tid >> 6] = x;
    __syncthreads();
    if (tid == 0) {
        int run = 0;
        #pragma unroll
        for (int w = 0; w < 4; ++w) { int t = wq[w]; wq[w] = run; run += t; }
    }
    __syncthreads();
    x += wq[tid >> 6];
    {
        const int grow = b * BROWS + tid;
        if (grow < N_NODES) rowptr[grow + 1] = s + x;
        if (b == 0 && tid == 0) rowptr[0] = 0;
        hx[tid] = s + (x - v);
    }
    __syncthreads();

    for (int i = tid; i < n; i += 256) {
        int2 d = tmp[s + i];
        unsigned int rl = ((unsigned)d.x) >> 17;
        int pos = atomicAdd(&hx[rl], 1);
        ec2[pos] = make_int2(d.x & 0x1FFFF, d.y);
    }
}

__global__ __launch_bounds__(256) void rowsort_g1(const int* __restrict__ bbase,
                                                  const int2* __restrict__ tmp,
                                                  int2* __restrict__ ec2,
                                                  int* __restrict__ rowptr,
                                                  const float* __restrict__ X,
                                                  const unsigned short* __restrict__ W1b,
                                                  unsigned short* __restrict__ Y) {
    extern __shared__ char sm[];
    if (blockIdx.x < GB1) gemm1_role(blockIdx.x, sm, X, W1b, Y);
    else                  rowsort_role(blockIdx.x - GB1, sm, bbase, tmp, ec2, rowptr);
}

// ---------------- gemm2 (template, bf16 A, pre-converted W): Y = X @ Wb -------------

template<int N, int K>
__global__ __launch_bounds__(256) void gemm_mfma(const unsigned short* __restrict__ X,
                                                 const unsigned short* __restrict__ Wb,
                                                 unsigned short* __restrict__ Y, int M) {
    __shared__ unsigned short bt[N * K];
    const int tid = threadIdx.x;

    {
        const int n = tid & (N - 1);
        const int kb = tid / N;
        const int kspan = K / (256 / N);
        for (int k0 = kb * kspan; k0 < (kb + 1) * kspan; k0 += 8) {
            unsigned short p[8];
            #pragma unroll
            for (int i = 0; i < 8; ++i) p[i] = Wb[(size_t)(k0 + i) * N + n];
            unsigned int byte = (unsigned int)n * (K * 2) + (unsigned int)k0 * 2;
            byte ^= (unsigned int)(n & 7) << 4;
            *(ushort8_t*)((char*)bt + byte) = *(const ushort8_t*)p;
        }
    }
    __syncthreads();

    const int lane = tid & 63;
    const int w = tid >> 6;
    const int rb = blockIdx.x * 128 + w * 32;
    const int lr = lane & 15;
    const int kg = lane >> 4;
    constexpr int NF = N / 16;
    constexpr int KS = K / 32;

    f32x4 acc[2][NF];
    #pragma unroll
    for (int a = 0; a < 2; ++a)
        #pragma unroll
        for (int nf = 0; nf < NF; ++nf)
            #pragma unroll
            for (int i = 0; i < 4; ++i) acc[a][nf][i] = 0.f;

    auto loadA = [&](int af, int ks) -> short8 {
        const int row = rb + af * 16 + lr;
        const int k0 = ks * 32 + kg * 8;
        short8 r;
        if (row < M) {
            r = *(const short8*)(X + (size_t)row * K + k0);
        } else {
            #pragma unroll
            for (int i = 0; i < 8; ++i) r[i] = 0;
        }
        return r;
    };
    auto loadB = [&](int nf, int ks) -> short8 {
        const int n = nf * 16 + lr;
        unsigned int byte = (unsigned int)n * (K * 2) + (unsigned int)(ks * 32 + kg * 8) * 2;
        byte ^= (unsigned int)(n & 7) << 4;
        return *(const short8*)((const char*)bt + byte);
    };

    #pragma unroll
    for (int ks = 0; ks < KS; ++ks) {
        short8 a0 = loadA(0, ks), a1 = loadA(1, ks);
        #pragma unroll
        for (int nf = 0; nf < NF; ++nf) {
            short8 bfr = loadB(nf, ks);
            acc[0][nf] = __builtin_amdgcn_mfma_f32_16x16x32_bf16(a0, bfr, acc[0][nf], 0, 0, 0);
            acc[1][nf] = __builtin_amdgcn_mfma_f32_16x16x32_bf16(a1, bfr, acc[1][nf], 0, 0, 0);
        }
    }

    #pragma unroll
    for (int af = 0; af < 2; ++af)
        #pragma unroll
        for (int nf = 0; nf < NF; ++nf)
            #pragma unroll
            for (int i = 0; i < 4; ++i) {
                const int r = rb + af * 16 + kg * 4 + i;
                if (r < M) Y[(size_t)r * N + nf * 16 + lr] = f2bf(acc[af][nf][i]);
            }
}

// ---------------- SpMM layer 1: F=128, full-wave 4B/lane, 16 gathers in flight ------

__global__ __launch_bounds__(256) void spmm1_kernel(const int* __restrict__ rp,
                                                    const int2* __restrict__ ec,
                                                    const unsigned int* __restrict__ d32,
                                                    const float* __restrict__ bias,
                                                    unsigned short* __restrict__ out) {
    const int lane = threadIdx.x & 63;
    const int row = blockIdx.x * 4 + (threadIdx.x >> 6);
    if (row >= N_NODES) return;
    const int s = __builtin_amdgcn_readfirstlane(rp[row]);
    const int e = __builtin_amdgcn_readfirstlane(rp[row + 1]);
    float a0 = 0.f, a1 = 0.f, b0 = 0.f, b1 = 0.f;
    float c0a = 0.f, c1a = 0.f, d0a = 0.f, d1a = 0.f;
    int j = s;
    for (; j + 16 <= e; j += 16) {
        int2 q0 = ec[j],      q1 = ec[j + 1],  q2 = ec[j + 2],  q3 = ec[j + 3];
        int2 q4 = ec[j + 4],  q5 = ec[j + 5],  q6 = ec[j + 6],  q7 = ec[j + 7];
        int2 q8 = ec[j + 8],  q9 = ec[j + 9],  qa = ec[j + 10], qb = ec[j + 11];
        int2 qc = ec[j + 12], qd = ec[j + 13], qe = ec[j + 14], qf = ec[j + 15];
        unsigned int u0 = d32[(size_t)q0.x * 64 + lane];
        unsigned int u1 = d32[(size_t)q1.x * 64 + lane];
        unsigned int u2 = d32[(size_t)q2.x * 64 + lane];
        unsigned int u3 = d32[(size_t)q3.x * 64 + lane];
        unsigned int u4 = d32[(size_t)q4.x * 64 + lane];
        unsigned int u5 = d32[(size_t)q5.x * 64 + lane];
        unsigned int u6 = d32[(size_t)q6.x * 64 + lane];
        unsigned int u7 = d32[(size_t)q7.x * 64 + lane];
        unsigned int u8 = d32[(size_t)q8.x * 64 + lane];
        unsigned int u9 = d32[(size_t)q9.x * 64 + lane];
        unsigned int ua = d32[(size_t)qa.x * 64 + lane];
        unsigned int ub = d32[(size_t)qb.x * 64 + lane];
        unsigned int uc = d32[(size_t)qc.x * 64 + lane];
        unsigned int ud = d32[(size_t)qd.x * 64 + lane];
        unsigned int ue = d32[(size_t)qe.x * 64 + lane];
        unsigned int uf = d32[(size_t)qf.x * 64 + lane];
        float v0 = __int_as_float(q0.y), v1 = __int_as_float(q1.y);
        float v2 = __int_as_float(q2.y), v3 = __int_as_float(q3.y);
        float v4 = __int_as_float(q4.y), v5 = __int_as_float(q5.y);
        float v6 = __int_as_float(q6.y), v7 = __int_as_float(q7.y);
        float v8 = __int_as_float(q8.y), v9 = __int_as_float(q9.y);
        float va = __int_as_float(qa.y), vb = __int_as_float(qb.y);
        float vc = __int_as_float(qc.y), vd = __int_as_float(qd.y);
        float ve = __int_as_float(qe.y), vf = __int_as_float(qf.y);
        a0 += v0 * bflo(u0); a1 += v0 * bfhi(u0);
        b0 += v1 * bflo(u1); b1 += v1 * bfhi(u1);
        c0a += v2 * bflo(u2); c1a += v2 * bfhi(u2);
        d0a += v3 * bflo(u3); d1a += v3 * bfhi(u3);
        a0 += v4 * bflo(u4); a1 += v4 * bfhi(u4);
        b0 += v5 * bflo(u5); b1 += v5 * bfhi(u5);
        c0a += v6 * bflo(u6); c1a += v6 * bfhi(u6);
        d0a += v7 * bflo(u7); d1a += v7 * bfhi(u7);
        a0 += v8 * bflo(u8); a1 += v8 * bfhi(u8);
        b0 += v9 * bflo(u9); b1 += v9 * bfhi(u9);
        c0a += va * bflo(ua); c1a += va * bfhi(ua);
        d0a += vb * bflo(ub); d1a += vb * bfhi(ub);
        a0 += vc * bflo(uc); a1 += vc * bfhi(uc);
        b0 += vd * bflo(ud); b1 += vd * bfhi(ud);
        c0a += ve * bflo(ue); c1a += ve * bfhi(ue);
        d0a += vf * bflo(uf); d1a += vf * bfhi(uf);
    }
    for (; j + 8 <= e; j += 8) {
        int2 q0 = ec[j],     q1 = ec[j + 1], q2 = ec[j + 2], q3 = ec[j + 3];
        int2 q4 = ec[j + 4], q5 = ec[j + 5], q6 = ec[j + 6], q7 = ec[j + 7];
        unsigned int u0 = d32[(size_t)q0.x * 64 + lane];
        unsigned int u1 = d32[(size_t)q1.x * 64 + lane];
        unsigned int u2 = d32[(size_t)q2.x * 64 + lane];
        unsigned int u3 = d32[(size_t)q3.x * 64 + lane];
        unsigned int u4 = d32[(size_t)q4.x * 64 + lane];
        unsigned int u5 = d32[(size_t)q5.x * 64 + lane];
        unsigned int u6 = d32[(size_t)q6.x * 64 + lane];
        unsigned int u7 = d32[(size_t)q7.x * 64 + lane];
        float v0 = __int_as_float(q0.y), v1 = __int_as_float(q1.y);
        float v2 = __int_as_float(q2.y), v3 = __int_as_float(q3.y);
        float v4 = __int_as_float(q4.y), v5 = __int_as_float(q5.y);
        float v6 = __int_as_float(q6.y), v7 = __int_as_float(q7.y);
        a0 += v0 * bflo(u0); a1 += v0 * bfhi(u0);
        b0 += v1 * bflo(u1); b1 += v1 * bfhi(u1);
        c0a += v2 * bflo(u2); c1a += v2 * bfhi(u2);
        d0a += v3 * bflo(u3); d1a += v3 * bfhi(u3);
        a0 += v4 * bflo(u4); a1 += v4 * bfhi(u4);
        b0 += v5 * bflo(u5); b1 += v5 * bfhi(u5);
        c0a += v6 * bflo(u6); c1a += v6 * bfhi(u6);
        d0a += v7 * bflo(u7); d1a += v7 * bfhi(u7);
    }
    for (; j < e; ++j) {
        int2 c = ec[j];
        float v = __int_as_float(c.y);
        unsigned int u = d32[(size_t)c.x * 64 + lane];
        a0 += v * bflo(u);
        a1 += v * bfhi(u);
    }
    a0 += b0 + c0a + d0a; a1 += b1 + c1a + d1a;
    float2 bp = *(const float2*)(bias + 2 * lane);
    float r0 = fmaxf(a0 + bp.x, 0.f);
    float r1 = fmaxf(a1 + bp.y, 0.f);
    unsigned int pack = (unsigned int)f2bf(r0) | ((unsigned int)f2bf(r1) << 16);
    *(unsigned int*)(out + (size_t)row * 128 + 2 * lane) = pack;
}

// ---------------- SpMM layer 2: F=64, half-wave 4B/lane, 16 edges (8/half) ----------

__global__ __launch_bounds__(256) void spmm2_kernel(const int* __restrict__ rp,
                                                    const int2* __restrict__ ec,
                                                    const unsigned int* __restrict__ d32,
                                                    const float* __restrict__ bias,
                                                    float* __restrict__ out) {
    const int lane = threadIdx.x & 63;
    const int row = blockIdx.x * 4 + (threadIdx.x >> 6);
    if (row >= N_NODES) return;
    const int s = __builtin_amdgcn_readfirstlane(rp[row]);
    const int e = __builtin_amdgcn_readfirstlane(rp[row + 1]);
    const int eh = lane >> 5, cl = lane & 31;
    float a0 = 0.f, a1 = 0.f, b0 = 0.f, b1 = 0.f;
    float c0a = 0.f, c1a = 0.f, d0a = 0.f, d1a = 0.f;
    int j = s;
    for (; j + 16 <= e; j += 16) {
        int2 q0 = ec[j + eh],      q1 = ec[j + 2 + eh];
        int2 q2 = ec[j + 4 + eh],  q3 = ec[j + 6 + eh];
        int2 q4 = ec[j + 8 + eh],  q5 = ec[j + 10 + eh];
        int2 q6 = ec[j + 12 + eh], q7 = ec[j + 14 + eh];
        unsigned int u0 = d32[(size_t)q0.x * 32 + cl];
        unsigned int u1 = d32[(size_t)q1.x * 32 + cl];
        unsigned int u2 = d32[(size_t)q2.x * 32 + cl];
        unsigned int u3 = d32[(size_t)q3.x * 32 + cl];
        unsigned int u4 = d32[(size_t)q4.x * 32 + cl];
        unsigned int u5 = d32[(size_t)q5.x * 32 + cl];
        unsigned int u6 = d32[(size_t)q6.x * 32 + cl];
        unsigned int u7 = d32[(size_t)q7.x * 32 + cl];
        float v0 = __int_as_float(q0.y), v1 = __int_as_float(q1.y);
        float v2 = __int_as_float(q2.y), v3 = __int_as_float(q3.y);
        float v4 = __int_as_float(q4.y), v5 = __int_as_float(q5.y);
        float v6 = __int_as_float(q6.y), v7 = __int_as_float(q7.y);
        a0 += v0 * bflo(u0); a1 += v0 * bfhi(u0);
        b0 += v1 * bflo(u1); b1 += v1 * bfhi(u1);
        c0a += v2 * bflo(u2); c1a += v2 * bfhi(u2);
        d0a += v3 * bflo(u3); d1a += v3 * bfhi(u3);
        a0 += v4 * bflo(u4); a1 += v4 * bfhi(u4);
        b0 += v5 * bflo(u5); b1 += v5 * bfhi(u5);
        c0a += v6 * bflo(u6); c1a += v6 * bfhi(u6);
        d0a += v7 * bflo(u7); d1a += v7 * bfhi(u7);
    }
    for (; j + 8 <= e; j += 8) {
        int2 q0 = ec[j + eh],     q1 = ec[j + 2 + eh];
        int2 q2 = ec[j + 4 + eh], q3 = ec[j + 6 + eh];
        unsigned int u0 = d32[(size_t)q0.x * 32 + cl];
        unsigned int u1 = d32[(size_t)q1.x * 32 + cl];
        unsigned int u2 = d32[(size_t)q2.x * 32 + cl];
        unsigned int u3 = d32[(size_t)q3.x * 32 + cl];
        float v0 = __int_as_float(q0.y), v1 = __int_as_float(q1.y);
        float v2 = __int_as_float(q2.y), v3 = __int_as_float(q3.y);
        a0 += v0 * bflo(u0); a1 += v0 * bfhi(u0);
        b0 += v1 * bflo(u1); b1 += v1 * bfhi(u1);
        c0a += v2 * bflo(u2); c1a += v2 * bfhi(u2);
        d0a += v3 * bflo(u3); d1a += v3 * bfhi(u3);
    }
    for (; j < e; j += 2) {
        const int j2 = j + eh;
        if (j2 < e) {
            int2 cv = ec[j2];
            float v = __int_as_float(cv.y);
            unsigned int u = d32[(size_t)cv.x * 32 + cl];
            a0 += v * bflo(u);
            a1 += v * bfhi(u);
        }
    }
    a0 += b0 + c0a + d0a; a1 += b1 + c1a + d1a;
    a0 += __shfl_xor(a0, 32);
    a1 += __shfl_xor(a1, 32);
    if (eh == 0) {
        float2 bp = *(const float2*)(bias + 2 * cl);
        *(float2*)(out + (size_t)row * 64 + 2 * cl) = make_float2(a0 + bp.x, a1 + bp.y);
    }
}

// ---------------- launch ----------------

extern "C" void kernel_launch(void* const* d_in, const int* in_sizes, int n_in,
                              void* d_out, int out_size, void* d_ws, size_t ws_size,
                              hipStream_t stream) {
    const float* x    = (const float*)d_in[0];
    const int*   erow = (const int*)d_in[1];
    const int*   ecol = (const int*)d_in[2];
    const float* evalv = (const float*)d_in[3];
    const float* W1   = (const float*)d_in[4];
    const float* b1   = (const float*)d_in[5];
    const float* W2   = (const float*)d_in[6];
    const float* b2   = (const float*)d_in[7];
    float* out = (float*)d_out;

    char* wsp = (char*)d_ws;
    size_t off = 0;
    auto alloc = [&](size_t bytes) -> void* {
        void* p = wsp + off;
        off = (off + bytes + 255) & ~(size_t)255;
        return p;
    };
    unsigned short* support = (unsigned short*)alloc((size_t)N_NODES * NHID * 2);
    unsigned short* hbuf    = (unsigned short*)alloc((size_t)N_NODES * NHID * 2);
    int2*  tmp     = (int2*)alloc((size_t)N_EDGES * 8);   // bucket-sorted (pass 1)
    int2*  ec2     = (int2*)alloc((size_t)N_EDGES * 8);   // row-sorted (pass 2)
    int*   Mt      = (int*)alloc((size_t)NBUCK * NBLK1 * 4);
    int*   btot    = (int*)alloc((size_t)NBUCK * 4);
    int*   bbase   = (int*)alloc((size_t)(NBUCK + 1) * 4);
    int*   rowptr  = (int*)alloc((size_t)(N_NODES + 1) * 4);
    unsigned short* W1b = (unsigned short*)alloc((size_t)NFEAT * NHID * 2);
    unsigned short* W2b = (unsigned short*)alloc((size_t)NHID * NOUT * 2);

    bcount_cvtw<<<NBLK1 + 128, 256, 0, stream>>>(erow, Mt, W1, W2, W1b, W2b);
    colscan_kernel<<<(NBUCK + 3) / 4, 256, 0, stream>>>(Mt, btot);
    bscan_kernel<<<1, 1024, 0, stream>>>(btot, bbase);
    binsort_kernel<<<NBLK1, 256, 0, stream>>>(erow, ecol, evalv, Mt, btot, bbase, tmp);
    rowsort_g1<<<GB1 + NBUCK, 256, 32768, stream>>>(bbase, tmp, ec2, rowptr,
                                                    x, W1b, support);

    spmm1_kernel<<<(N_NODES + 3) / 4, 256, 0, stream>>>(rowptr, ec2, (const unsigned int*)support, b1, hbuf);
    gemm_mfma<NOUT, NHID><<<(N_NODES + 127) / 128, 256, 0, stream>>>(hbuf, W2b, support, N_NODES);
    spmm2_kernel<<<(N_NODES + 3) / 4, 256, 0, stream>>>(rowptr, ec2, (const unsigned int*)support, b2, out);
}